// Round 6
// baseline (1995.057 us; speedup 1.0000x reference)
//
#include <hip/hip_runtime.h>
#include <hip/hip_bf16.h>
#include <math.h>

// ---------------- problem constants ----------------
#define T_TOKENS 8192          // B*S = 4*2048
#define D_MODEL  1024
#define N_EXP    8
#define I_RAW    2752
#define I_PAD    2816          // 88 * 32
#define N_CAT    5632          // 2 * I_PAD (gate/up interleaved in 32-blocks)
#define MAXROWS  18432         // 72 * 256 >= 16384 + 8*255
#define NYT      72
#define DUMP_SID (2 * T_TOKENS)

typedef __attribute__((ext_vector_type(8))) short bf16x8;
typedef __attribute__((ext_vector_type(8))) unsigned short ushort8;
typedef __attribute__((ext_vector_type(4))) float f32x4;
typedef unsigned short ushort_t;

// ctrl layout (ints): [0..7] counts, [8..15] cursor, [16..24] seg offsets,
// [32..103] ytile -> expert table (-1 = inactive)
#define CTRL_COUNT 0
#define CTRL_CUR   8
#define CTRL_SEG   16
#define CTRL_YT    32

#define VMW(n)  asm volatile("s_waitcnt vmcnt(" n ")" ::: "memory")
#define BARRIER() asm volatile("s_barrier" ::: "memory")

__device__ __forceinline__ void gll16(const void* g, void* l) {
  __builtin_amdgcn_global_load_lds(
      (const __attribute__((address_space(1))) void*)g,
      (__attribute__((address_space(3))) void*)l, 16, 0, 0);
}

__device__ __forceinline__ float silu_mul(float g, float u) {
  return g / (1.f + __expf(-g)) * u;
}

__device__ __forceinline__ float bf2f(ushort_t u) {
  return __uint_as_float((unsigned)u << 16);
}

// ---------------- router: one wave per token ----------------
__global__ void __launch_bounds__(64) router_kernel(
    const float* __restrict__ x, const float* __restrict__ rw,
    int* __restrict__ topidx, float* __restrict__ topw, int* __restrict__ ctrl) {
  const int t = blockIdx.x;
  const int lane = threadIdx.x;
  const float* xr = x + (size_t)t * D_MODEL;
  float acc[N_EXP];
#pragma unroll
  for (int e = 0; e < N_EXP; ++e) acc[e] = 0.f;
  for (int d = lane; d < D_MODEL; d += 64) {
    const float xv = xr[d];
    const float* r = rw + (size_t)d * N_EXP;
#pragma unroll
    for (int e = 0; e < N_EXP; ++e) acc[e] = fmaf(xv, r[e], acc[e]);
  }
#pragma unroll
  for (int e = 0; e < N_EXP; ++e) {
    for (int off = 32; off > 0; off >>= 1) acc[e] += __shfl_xor(acc[e], off, 64);
  }
  if (lane == 0) {
    float m = acc[0];
#pragma unroll
    for (int e = 1; e < N_EXP; ++e) m = fmaxf(m, acc[e]);
    float p[N_EXP], s = 0.f;
#pragma unroll
    for (int e = 0; e < N_EXP; ++e) { p[e] = expf(acc[e] - m); s += p[e]; }
    int i0 = 0; float v0 = p[0];
#pragma unroll
    for (int e = 1; e < N_EXP; ++e) if (p[e] > v0) { v0 = p[e]; i0 = e; }
    int i1 = -1; float v1 = -1.f;
#pragma unroll
    for (int e = 0; e < N_EXP; ++e) if (e != i0 && p[e] > v1) { v1 = p[e]; i1 = e; }
    v0 /= s; v1 /= s;
    const float r = v0 + v1 + 1e-6f;
    v0 /= r; v1 /= r;
    topidx[t * 2] = i0; topidx[t * 2 + 1] = i1;
    topw[t * 2] = v0;  topw[t * 2 + 1] = v1;
    atomicAdd(&ctrl[CTRL_COUNT + i0], 1);
    atomicAdd(&ctrl[CTRL_COUNT + i1], 1);
  }
}

// ---------------- x -> bf16 ----------------
__global__ void cvt_x_kernel(const float* __restrict__ x,
                             __hip_bfloat16* __restrict__ xb, int n4) {
  const int i = blockIdx.x * blockDim.x + threadIdx.x;
  if (i < n4) {
    const float4 v = ((const float4*)x)[i];
    __hip_bfloat16 b0 = __float2bfloat16(v.x), b1 = __float2bfloat16(v.y);
    __hip_bfloat16 b2 = __float2bfloat16(v.z), b3 = __float2bfloat16(v.w);
    ushort4 o;
    o.x = reinterpret_cast<ushort_t&>(b0); o.y = reinterpret_cast<ushort_t&>(b1);
    o.z = reinterpret_cast<ushort_t&>(b2); o.w = reinterpret_cast<ushort_t&>(b3);
    ((ushort4*)xb)[i] = o;
  }
}

// ---------------- transpose + convert, 64x64 tiles, vectorized ----------------
__global__ void __launch_bounds__(256) transpose_cvt_kernel(
    const float* __restrict__ in, __hip_bfloat16* __restrict__ out,
    int Rin, int Cin, int Co, long in_es, long out_es, int mode) {
  __shared__ float tile[64][65];
  const float* inp = in + (size_t)blockIdx.z * in_es;
  __hip_bfloat16* outp = out + (size_t)blockIdx.z * out_es;
  const int b0 = blockIdx.x * 64;   // input-row / out-col tile
  const int a0 = blockIdx.y * 64;   // input-col / out-row tile
  const int tid = threadIdx.x;
  const bool inb = (b0 < Rin) && (a0 < Cin);
  const int bi0 = tid >> 4, a4 = (tid & 15) * 4;
  if (inb) {
#pragma unroll
    for (int i = 0; i < 4; ++i) {
      const int bi = bi0 + i * 16;
      const float4 v = *(const float4*)&inp[(size_t)(b0 + bi) * Cin + a0 + a4];
      tile[bi][a4] = v.x; tile[bi][a4 + 1] = v.y;
      tile[bi][a4 + 2] = v.z; tile[bi][a4 + 3] = v.w;
    }
  } else {
#pragma unroll
    for (int i = 0; i < 4; ++i) {
      const int bi = bi0 + i * 16;
      tile[bi][a4] = 0.f; tile[bi][a4 + 1] = 0.f;
      tile[bi][a4 + 2] = 0.f; tile[bi][a4 + 3] = 0.f;
    }
  }
  __syncthreads();
#pragma unroll
  for (int half = 0; half < 2; ++half) {
    const int g = tid + half * 256;
    const int al = g >> 3, bc = (g & 7) * 8;
    ushort8 o;
#pragma unroll
    for (int j = 0; j < 8; ++j) {
      __hip_bfloat16 h = __float2bfloat16(tile[bc + j][al]);
      o[j] = *(const ushort_t*)&h;
    }
    const int a = a0 + al;
    int A;
    if (mode == 0) A = a;
    else A = ((a >> 5) << 6) + ((mode == 2) ? 32 : 0) + (a & 31);
    *(ushort8*)&outp[(size_t)A * Co + b0 + bc] = o;
  }
}

// ---------------- pad fill: pads point at the dump slot ----------------
__global__ void padfill_kernel(int* __restrict__ rowmap, float* __restrict__ roww) {
  const int i = blockIdx.x * blockDim.x + threadIdx.x;
  if (i < MAXROWS) { rowmap[i] = DUMP_SID; roww[i] = 0.f; }
}

// ---------------- scan: seg offsets + ytile table ----------------
__global__ void scan_kernel(int* __restrict__ ctrl) {
  if (threadIdx.x == 0 && blockIdx.x == 0) {
    int s = 0, yt = 0;
    ctrl[CTRL_SEG] = 0;
    for (int e = 0; e < N_EXP; ++e) {
      const int c = ctrl[CTRL_COUNT + e];
      const int padded = (c + 255) & ~255;
      const int n = padded >> 8;
      for (int j = 0; j < n; ++j) ctrl[CTRL_YT + yt + j] = e;
      yt += n;
      s += padded;
      ctrl[CTRL_SEG + 1 + e] = s;
    }
    for (; yt < NYT; ++yt) ctrl[CTRL_YT + yt] = -1;
  }
}

// ---------------- scatter ----------------
__global__ void scatter_kernel(const int* __restrict__ topidx, const float* __restrict__ topw,
                               int* __restrict__ ctrl, int* __restrict__ rowmap,
                               float* __restrict__ roww) {
  const int t = blockIdx.x * blockDim.x + threadIdx.x;
  if (t >= T_TOKENS) return;
#pragma unroll
  for (int k = 0; k < 2; ++k) {
    const int e = topidx[t * 2 + k];
    const int pos = ctrl[CTRL_SEG + e] + atomicAdd(&ctrl[CTRL_CUR + e], 1);
    rowmap[pos] = t * 2 + k;
    roww[pos] = topw[t * 2 + k];
  }
}

// =====================================================================
// GEMM1: 256x512 tile, wave=128x128, BK=32 x 3-slot ring, 2 phases/slot,
// VMW(6) never-0.  Chunk swizzle: logical k-chunk kc of row r at physical
// (kc + (r>>1)) & 3 (inverse applied to global source; verified 0-conflict).
// XCD mapping: xcd=b&7, w=b>>3; yt=xcd*9+w%9 (A/B L2 reuse), xn=w/9.
// Epilogue: H = w_route * silu(gate)*up.
// =====================================================================
__global__ void __launch_bounds__(512, 1) gemm1_kernel(
    const __hip_bfloat16* __restrict__ xb,
    const __hip_bfloat16* __restrict__ wcat,
    __hip_bfloat16* __restrict__ H,
    const int* __restrict__ rowmap, const float* __restrict__ roww,
    const int* __restrict__ ctrl) {
  const unsigned b = blockIdx.x;      // 792 blocks
  const int xcd = b & 7;
  const unsigned w = b >> 3;          // 0..98
  const int xn = (int)(w / 9);        // 0..10
  const int yt = xcd * 9 + (int)(w % 9);
  const int e = ctrl[CTRL_YT + yt];
  if (e < 0) return;
  const int row0 = yt * 256;
  const int nbase = xn * 512;
  const int tid = threadIdx.x, lane = tid & 63, wid = tid >> 6;
  const int wrm = (wid >> 2) * 128, wrn = (wid & 3) * 128;

  __shared__ __align__(16) __hip_bfloat16 sA[3][8192];    // 256 x 32 per slot
  __shared__ __align__(16) __hip_bfloat16 sB[3][16384];   // 512 x 32 per slot
  __shared__ float sW[256];

  if (tid < 256) sW[tid] = roww[row0 + tid];

  const int srow = tid >> 2;
  const int kc = ((tid & 3) - ((tid >> 3) & 3)) & 3;   // inverse swizzle on source
  int tok0 = rowmap[row0 + srow] >> 1;
  int tok1 = rowmap[row0 + 128 + srow] >> 1;
  tok0 = min(tok0, T_TOKENS - 1);   // pads -> any valid row; sW=0 zeroes H
  tok1 = min(tok1, T_TOKENS - 1);
  const __hip_bfloat16* gA0 = xb + (size_t)tok0 * D_MODEL + kc * 8;
  const __hip_bfloat16* gA1 = xb + (size_t)tok1 * D_MODEL + kc * 8;
  const __hip_bfloat16* gB = wcat + ((size_t)e * N_CAT + nbase + srow) * D_MODEL + kc * 8;

  __syncthreads();   // sW visible; drains scalar-path loads so vmcnt starts clean

  auto stageA = [&](int sl, int kt) {
    gll16(gA0 + kt * 32, &sA[sl][tid * 8]);
    gll16(gA1 + kt * 32, &sA[sl][4096 + tid * 8]);
  };
  auto stageBlo = [&](int sl, int kt) {
    gll16(gB + kt * 32, &sB[sl][tid * 8]);
    gll16(gB + (size_t)128 * D_MODEL + kt * 32, &sB[sl][4096 + tid * 8]);
  };
  auto stageBhi = [&](int sl, int kt) {
    gll16(gB + (size_t)256 * D_MODEL + kt * 32, &sB[sl][8192 + tid * 8]);
    gll16(gB + (size_t)384 * D_MODEL + kt * 32, &sB[sl][12288 + tid * 8]);
  };

  f32x4 acc[8][8];
  const f32x4 z4 = {0.f, 0.f, 0.f, 0.f};
#pragma unroll
  for (int a = 0; a < 8; ++a)
#pragma unroll
    for (int c = 0; c < 8; ++c) acc[a][c] = z4;

  const int poff = ((lane >> 4) + ((lane & 15) >> 1)) & 3;
  const int aoff = (wrm + (lane & 15)) * 32 + poff * 8;
  const int boff = (wrn + (lane & 15)) * 32 + poff * 8;

  const int NT = D_MODEL / 32;  // 32 slots
  stageA(0, 0); stageBlo(0, 0); stageBhi(0, 0);
  stageA(1, 1); stageBlo(1, 1); stageBhi(1, 1);
  VMW("6"); BARRIER();

  int sl = 0;
  for (int t = 0; t < NT; ++t) {
    const int sl2 = (sl + 2 >= 3) ? sl - 1 : sl + 2;
    const int kt2 = (t + 2 < NT) ? t + 2 : t + 2 - NT;   // wrap (harmless restage)
    bf16x8 af[8], bf[4];
    // ---- PH-a: A frags + B lo ----
#pragma unroll
    for (int mi = 0; mi < 8; ++mi) af[mi] = *(const bf16x8*)&sA[sl][aoff + mi * 512];
#pragma unroll
    for (int q = 0; q < 4; ++q) bf[q] = *(const bf16x8*)&sB[sl][boff + q * 512];
    stageA(sl2, kt2); stageBlo(sl2, kt2);
    BARRIER();
    __builtin_amdgcn_s_setprio(1);
#pragma unroll
    for (int mi = 0; mi < 8; ++mi)
#pragma unroll
      for (int q = 0; q < 4; ++q)
        acc[mi][q] = __builtin_amdgcn_mfma_f32_16x16x32_bf16(af[mi], bf[q], acc[mi][q], 0, 0, 0);
    __builtin_amdgcn_s_setprio(0);
    BARRIER();
    // ---- PH-b: B hi ----
#pragma unroll
    for (int q = 0; q < 4; ++q) bf[q] = *(const bf16x8*)&sB[sl][boff + (4 + q) * 512];
    stageBhi(sl2, kt2);
    VMW("6");
    BARRIER();
    __builtin_amdgcn_s_setprio(1);
#pragma unroll
    for (int mi = 0; mi < 8; ++mi)
#pragma unroll
      for (int q = 0; q < 4; ++q)
        acc[mi][4 + q] = __builtin_amdgcn_mfma_f32_16x16x32_bf16(af[mi], bf[q], acc[mi][4 + q], 0, 0, 0);
    __builtin_amdgcn_s_setprio(0);
    BARRIER();
    sl = (sl + 1 >= 3) ? 0 : sl + 1;
  }
  VMW("0");

  // epilogue: cols alternate 32-gate/32-up within 64-groups.
  // pair p in {0,1}: gate ni=p*4+q, up ni=p*4+2+q (q in {0,1})
  const int hbase = ((nbase + wrn) >> 6) * 32;
#pragma unroll
  for (int mi = 0; mi < 8; ++mi) {
    const int r0 = wrm + mi * 16 + ((lane >> 4) * 4);
#pragma unroll
    for (int p = 0; p < 2; ++p) {
#pragma unroll
      for (int q = 0; q < 2; ++q) {
        const int hcol = hbase + p * 32 + q * 16 + (lane & 15);
        const f32x4 g = acc[mi][p * 4 + q], u = acc[mi][p * 4 + 2 + q];
#pragma unroll
        for (int j = 0; j < 4; ++j) {
          const float h = silu_mul(g[j], u[j]) * sW[r0 + j];
          H[(size_t)(row0 + r0 + j) * I_PAD + hcol] = __float2bfloat16(h);
        }
      }
    }
  }
}

// =====================================================================
// GEMM2: 256x256 tile, wave=128x64, BK=32 x 3-slot ring, VMW(4).
// slot[sid] = (H @ Wd) row slice (bf16 plain stores). H pre-scaled.
// Mapping: xcd=b&7, w=b>>3 (0..35); yt=xcd*9+w%9, xn=w/9 (0..3).
// =====================================================================
__global__ void __launch_bounds__(512, 1) gemm2_kernel(
    const __hip_bfloat16* __restrict__ H,
    const __hip_bfloat16* __restrict__ wdt,   // [E][D][I_PAD] n-major
    ushort_t* __restrict__ slot,              // [2T+1][D] bf16 bits
    const int* __restrict__ rowmap, const int* __restrict__ ctrl) {
  const unsigned b = blockIdx.x;      // 288 blocks
  const int xcd = b & 7;
  const unsigned w = b >> 3;          // 0..35
  const int xn = (int)(w / 9);        // 0..3
  const int yt = xcd * 9 + (int)(w % 9);
  const int e = ctrl[CTRL_YT + yt];
  if (e < 0) return;
  const int row0 = yt * 256;
  const int nbase = xn * 256;
  const int tid = threadIdx.x, lane = tid & 63, wid = tid >> 6;
  const int wrm = (wid >> 2) * 128, wrn = (wid & 3) * 64;

  __shared__ __align__(16) __hip_bfloat16 sA[3][8192];    // 256 x 32
  __shared__ __align__(16) __hip_bfloat16 sB[3][8192];    // 256 x 32
  __shared__ int sTok[256];

  if (tid < 256) sTok[tid] = rowmap[row0 + tid];

  const int srow = tid >> 2;
  const int kc = ((tid & 3) - ((tid >> 3) & 3)) & 3;
  const __hip_bfloat16* gA0 = H + (size_t)(row0 + srow) * I_PAD + kc * 8;
  const __hip_bfloat16* gA1 = gA0 + (size_t)128 * I_PAD;
  const __hip_bfloat16* gB0 = wdt + ((size_t)e * D_MODEL + nbase + srow) * I_PAD + kc * 8;
  const __hip_bfloat16* gB1 = gB0 + (size_t)128 * I_PAD;

  __syncthreads();

  auto stageA = [&](int sl, int kt) {
    gll16(gA0 + kt * 32, &sA[sl][tid * 8]);
    gll16(gA1 + kt * 32, &sA[sl][4096 + tid * 8]);
  };
  auto stageB = [&](int sl, int kt) {
    gll16(gB0 + kt * 32, &sB[sl][tid * 8]);
    gll16(gB1 + kt * 32, &sB[sl][4096 + tid * 8]);
  };

  f32x4 acc[8][4];
  const f32x4 z4 = {0.f, 0.f, 0.f, 0.f};
#pragma unroll
  for (int a = 0; a < 8; ++a)
#pragma unroll
    for (int c = 0; c < 4; ++c) acc[a][c] = z4;

  const int poff = ((lane >> 4) + ((lane & 15) >> 1)) & 3;
  const int aoff = (wrm + (lane & 15)) * 32 + poff * 8;
  const int boff = (wrn + (lane & 15)) * 32 + poff * 8;

  const int NT = I_PAD / 32;  // 88 slots
  stageA(0, 0); stageB(0, 0);
  stageA(1, 1); stageB(1, 1);
  VMW("4"); BARRIER();

  int sl = 0;
  for (int t = 0; t < NT; ++t) {
    const int sl2 = (sl + 2 >= 3) ? sl - 1 : sl + 2;
    const int kt2 = (t + 2 < NT) ? t + 2 : t + 2 - NT;
    bf16x8 af[8], bf[2];
    // ---- PH-a ----
#pragma unroll
    for (int mi = 0; mi < 8; ++mi) af[mi] = *(const bf16x8*)&sA[sl][aoff + mi * 512];
#pragma unroll
    for (int q = 0; q < 2; ++q) bf[q] = *(const bf16x8*)&sB[sl][boff + q * 512];
    stageA(sl2, kt2);
    BARRIER();
    __builtin_amdgcn_s_setprio(1);
#pragma unroll
    for (int mi = 0; mi < 8; ++mi)
#pragma unroll
      for (int q = 0; q < 2; ++q)
        acc[mi][q] = __builtin_amdgcn_mfma_f32_16x16x32_bf16(af[mi], bf[q], acc[mi][q], 0, 0, 0);
    __builtin_amdgcn_s_setprio(0);
    BARRIER();
    // ---- PH-b ----
#pragma unroll
    for (int q = 0; q < 2; ++q) bf[q] = *(const bf16x8*)&sB[sl][boff + (2 + q) * 512];
    stageB(sl2, kt2);
    VMW("4");
    BARRIER();
    __builtin_amdgcn_s_setprio(1);
#pragma unroll
    for (int mi = 0; mi < 8; ++mi)
#pragma unroll
      for (int q = 0; q < 2; ++q)
        acc[mi][2 + q] = __builtin_amdgcn_mfma_f32_16x16x32_bf16(af[mi], bf[q], acc[mi][2 + q], 0, 0, 0);
    __builtin_amdgcn_s_setprio(0);
    BARRIER();
    sl = (sl + 1 >= 3) ? 0 : sl + 1;
  }
  VMW("0");

#pragma unroll
  for (int mi = 0; mi < 8; ++mi) {
    const int r0 = wrm + mi * 16 + ((lane >> 4) * 4);
#pragma unroll
    for (int ni = 0; ni < 4; ++ni) {
      const int col = nbase + wrn + ni * 16 + (lane & 15);
#pragma unroll
      for (int j = 0; j < 4; ++j) {
        const int sid = sTok[r0 + j];
        __hip_bfloat16 hv = __float2bfloat16(acc[mi][ni][j]);
        slot[(size_t)sid * D_MODEL + col] = *(const ushort_t*)&hv;
      }
    }
  }
}

// ---------------- combine: out[t] = slot[2t] + slot[2t+1] ----------------
__global__ void __launch_bounds__(256) combine_kernel(
    const ushort_t* __restrict__ slot, float* __restrict__ out) {
  const int i = blockIdx.x * 256 + threadIdx.x;   // over T*D/8
  const int t = i >> 7;
  const int c = (i & 127) << 3;
  const size_t b0 = ((size_t)(t << 1)) * D_MODEL + c;
  const ushort8 a = *(const ushort8*)&slot[b0];
  const ushort8 b = *(const ushort8*)&slot[b0 + D_MODEL];
  float4 o0, o1;
  o0.x = bf2f(a[0]) + bf2f(b[0]); o0.y = bf2f(a[1]) + bf2f(b[1]);
  o0.z = bf2f(a[2]) + bf2f(b[2]); o0.w = bf2f(a[3]) + bf2f(b[3]);
  o1.x = bf2f(a[4]) + bf2f(b[4]); o1.y = bf2f(a[5]) + bf2f(b[5]);
  o1.z = bf2f(a[6]) + bf2f(b[6]); o1.w = bf2f(a[7]) + bf2f(b[7]);
  ((float4*)out)[i * 2] = o0;
  ((float4*)out)[i * 2 + 1] = o1;
}

// ---------------- launch ----------------
extern "C" void kernel_launch(void* const* d_in, const int* in_sizes, int n_in,
                              void* d_out, int out_size, void* d_ws, size_t ws_size,
                              hipStream_t stream) {
  (void)in_sizes; (void)n_in; (void)ws_size; (void)out_size;
  const float* x  = (const float*)d_in[0];
  const float* rw = (const float*)d_in[1];
  const float* wg = (const float*)d_in[2];
  const float* wu = (const float*)d_in[3];
  const float* wd = (const float*)d_in[4];
  float* out = (float*)d_out;

  char* ws = (char*)d_ws;
  size_t off = 0;
  auto alloc = [&](size_t bytes) -> char* {
    char* p = ws + off;
    off += (bytes + 255) & ~(size_t)255;
    return p;
  };

  int*   ctrl   = (int*)alloc(512);
  int*   topidx = (int*)alloc((size_t)T_TOKENS * 2 * 4);
  float* topw   = (float*)alloc((size_t)T_TOKENS * 2 * 4);
  int*   rowmap = (int*)alloc((size_t)MAXROWS * 4);
  float* roww   = (float*)alloc((size_t)MAXROWS * 4);
  __hip_bfloat16* xb   = (__hip_bfloat16*)alloc((size_t)T_TOKENS * D_MODEL * 2);
  __hip_bfloat16* wcat = (__hip_bfloat16*)alloc((size_t)N_EXP * N_CAT * D_MODEL * 2);
  __hip_bfloat16* Hbuf = (__hip_bfloat16*)alloc((size_t)MAXROWS * I_PAD * 2);
  ushort_t* slotout = (ushort_t*)alloc((size_t)(2 * T_TOKENS + 1) * D_MODEL * 2);
  // wdt aliases wcat (wcat dead after gemm1; wdt transpose runs after gemm1)
  __hip_bfloat16* wdt = wcat;

  hipMemsetAsync(ctrl, 0, 256, stream);

  cvt_x_kernel<<<(T_TOKENS * D_MODEL / 4 + 255) / 256, 256, 0, stream>>>(
      x, xb, T_TOKENS * D_MODEL / 4);

  // wg [E][1024][2752] -> wcat gate rows; wu -> wcat up rows
  transpose_cvt_kernel<<<dim3(D_MODEL / 64, I_PAD / 64, N_EXP), 256, 0, stream>>>(
      wg, wcat, D_MODEL, I_RAW, D_MODEL, (long)D_MODEL * I_RAW, (long)N_CAT * D_MODEL, 1);
  transpose_cvt_kernel<<<dim3(D_MODEL / 64, I_PAD / 64, N_EXP), 256, 0, stream>>>(
      wu, wcat, D_MODEL, I_RAW, D_MODEL, (long)D_MODEL * I_RAW, (long)N_CAT * D_MODEL, 2);

  router_kernel<<<T_TOKENS, 64, 0, stream>>>(x, rw, topidx, topw, ctrl);
  padfill_kernel<<<(MAXROWS + 255) / 256, 256, 0, stream>>>(rowmap, roww);
  scan_kernel<<<1, 64, 0, stream>>>(ctrl);
  scatter_kernel<<<(T_TOKENS + 255) / 256, 256, 0, stream>>>(topidx, topw, ctrl, rowmap, roww);

  gemm1_kernel<<<dim3(NYT * 11), 512, 0, stream>>>(
      xb, wcat, Hbuf, rowmap, roww, ctrl);

  // wd [E][2752][1024] -> wdt [E][1024][2816]  (into wcat's space, after gemm1)
  transpose_cvt_kernel<<<dim3(I_PAD / 64, D_MODEL / 64, N_EXP), 256, 0, stream>>>(
      wd, wdt, I_RAW, D_MODEL, I_PAD, (long)I_RAW * D_MODEL, (long)D_MODEL * I_PAD, 0);

  gemm2_kernel<<<dim3(NYT * 4), 512, 0, stream>>>(
      Hbuf, wdt, slotout, rowmap, ctrl);

  combine_kernel<<<(T_TOKENS * D_MODEL / 8) / 256, 256, 0, stream>>>(slotout, out);
}

// Round 7
// 773.070 us; speedup vs baseline: 2.5807x; 2.5807x over previous
//
#include <hip/hip_runtime.h>
#include <hip/hip_bf16.h>
#include <math.h>

// ---------------- problem constants ----------------
#define T_TOKENS 8192          // B*S = 4*2048
#define D_MODEL  1024
#define N_EXP    8
#define I_RAW    2752
#define I_PAD    2816          // 88 * 32
#define N_CAT    5632          // 2 * I_PAD (gate/up interleaved in 32-blocks)
#define MAXROWS  18432         // 72 * 256 >= 16384 + 8*255
#define NYT      72
#define DUMP_SID (2 * T_TOKENS)

typedef __attribute__((ext_vector_type(8))) short bf16x8;
typedef __attribute__((ext_vector_type(8))) unsigned short ushort8;
typedef __attribute__((ext_vector_type(4))) float f32x4;
typedef unsigned short ushort_t;

// ctrl layout (ints): [0..7] counts, [8..15] cursor, [16..24] seg offsets,
// [32..103] ytile -> expert table (-1 = inactive)
#define CTRL_COUNT 0
#define CTRL_CUR   8
#define CTRL_SEG   16
#define CTRL_YT    32

#define VMW(n)  asm volatile("s_waitcnt vmcnt(" n ")" ::: "memory")
#define BARRIER() asm volatile("s_barrier" ::: "memory")

__device__ __forceinline__ void gll16(const void* g, void* l) {
  __builtin_amdgcn_global_load_lds(
      (const __attribute__((address_space(1))) void*)g,
      (__attribute__((address_space(3))) void*)l, 16, 0, 0);
}

__device__ __forceinline__ float silu_mul(float g, float u) {
  return g / (1.f + __expf(-g)) * u;
}

__device__ __forceinline__ float bf2f(ushort_t u) {
  return __uint_as_float((unsigned)u << 16);
}

// ---------------- router: one wave per token ----------------
__global__ void __launch_bounds__(64) router_kernel(
    const float* __restrict__ x, const float* __restrict__ rw,
    int* __restrict__ topidx, float* __restrict__ topw, int* __restrict__ ctrl) {
  const int t = blockIdx.x;
  const int lane = threadIdx.x;
  const float* xr = x + (size_t)t * D_MODEL;
  float acc[N_EXP];
#pragma unroll
  for (int e = 0; e < N_EXP; ++e) acc[e] = 0.f;
  for (int d = lane; d < D_MODEL; d += 64) {
    const float xv = xr[d];
    const float* r = rw + (size_t)d * N_EXP;
#pragma unroll
    for (int e = 0; e < N_EXP; ++e) acc[e] = fmaf(xv, r[e], acc[e]);
  }
#pragma unroll
  for (int e = 0; e < N_EXP; ++e) {
    for (int off = 32; off > 0; off >>= 1) acc[e] += __shfl_xor(acc[e], off, 64);
  }
  if (lane == 0) {
    float m = acc[0];
#pragma unroll
    for (int e = 1; e < N_EXP; ++e) m = fmaxf(m, acc[e]);
    float p[N_EXP], s = 0.f;
#pragma unroll
    for (int e = 0; e < N_EXP; ++e) { p[e] = expf(acc[e] - m); s += p[e]; }
    int i0 = 0; float v0 = p[0];
#pragma unroll
    for (int e = 1; e < N_EXP; ++e) if (p[e] > v0) { v0 = p[e]; i0 = e; }
    int i1 = -1; float v1 = -1.f;
#pragma unroll
    for (int e = 0; e < N_EXP; ++e) if (e != i0 && p[e] > v1) { v1 = p[e]; i1 = e; }
    v0 /= s; v1 /= s;
    const float r = v0 + v1 + 1e-6f;
    v0 /= r; v1 /= r;
    topidx[t * 2] = i0; topidx[t * 2 + 1] = i1;
    topw[t * 2] = v0;  topw[t * 2 + 1] = v1;
    atomicAdd(&ctrl[CTRL_COUNT + i0], 1);
    atomicAdd(&ctrl[CTRL_COUNT + i1], 1);
  }
}

// ---------------- x -> bf16 ----------------
__global__ void cvt_x_kernel(const float* __restrict__ x,
                             __hip_bfloat16* __restrict__ xb, int n4) {
  const int i = blockIdx.x * blockDim.x + threadIdx.x;
  if (i < n4) {
    const float4 v = ((const float4*)x)[i];
    __hip_bfloat16 b0 = __float2bfloat16(v.x), b1 = __float2bfloat16(v.y);
    __hip_bfloat16 b2 = __float2bfloat16(v.z), b3 = __float2bfloat16(v.w);
    ushort4 o;
    o.x = reinterpret_cast<ushort_t&>(b0); o.y = reinterpret_cast<ushort_t&>(b1);
    o.z = reinterpret_cast<ushort_t&>(b2); o.w = reinterpret_cast<ushort_t&>(b3);
    ((ushort4*)xb)[i] = o;
  }
}

// ---------------- transpose + convert, 64x64 tiles, vectorized ----------------
__global__ void __launch_bounds__(256) transpose_cvt_kernel(
    const float* __restrict__ in, __hip_bfloat16* __restrict__ out,
    int Rin, int Cin, int Co, long in_es, long out_es, int mode) {
  __shared__ float tile[64][65];
  const float* inp = in + (size_t)blockIdx.z * in_es;
  __hip_bfloat16* outp = out + (size_t)blockIdx.z * out_es;
  const int b0 = blockIdx.x * 64;   // input-row / out-col tile
  const int a0 = blockIdx.y * 64;   // input-col / out-row tile
  const int tid = threadIdx.x;
  const bool inb = (b0 < Rin) && (a0 < Cin);
  const int bi0 = tid >> 4, a4 = (tid & 15) * 4;
  if (inb) {
#pragma unroll
    for (int i = 0; i < 4; ++i) {
      const int bi = bi0 + i * 16;
      const float4 v = *(const float4*)&inp[(size_t)(b0 + bi) * Cin + a0 + a4];
      tile[bi][a4] = v.x; tile[bi][a4 + 1] = v.y;
      tile[bi][a4 + 2] = v.z; tile[bi][a4 + 3] = v.w;
    }
  } else {
#pragma unroll
    for (int i = 0; i < 4; ++i) {
      const int bi = bi0 + i * 16;
      tile[bi][a4] = 0.f; tile[bi][a4 + 1] = 0.f;
      tile[bi][a4 + 2] = 0.f; tile[bi][a4 + 3] = 0.f;
    }
  }
  __syncthreads();
#pragma unroll
  for (int half = 0; half < 2; ++half) {
    const int g = tid + half * 256;
    const int al = g >> 3, bc = (g & 7) * 8;
    ushort8 o;
#pragma unroll
    for (int j = 0; j < 8; ++j) {
      __hip_bfloat16 h = __float2bfloat16(tile[bc + j][al]);
      o[j] = *(const ushort_t*)&h;
    }
    const int a = a0 + al;
    int A;
    if (mode == 0) A = a;
    else A = ((a >> 5) << 6) + ((mode == 2) ? 32 : 0) + (a & 31);
    *(ushort8*)&outp[(size_t)A * Co + b0 + bc] = o;
  }
}

// ---------------- pad fill: pads point at the dump slot ----------------
__global__ void padfill_kernel(int* __restrict__ rowmap, float* __restrict__ roww) {
  const int i = blockIdx.x * blockDim.x + threadIdx.x;
  if (i < MAXROWS) { rowmap[i] = DUMP_SID; roww[i] = 0.f; }
}

// ---------------- scan: seg offsets + ytile table ----------------
__global__ void scan_kernel(int* __restrict__ ctrl) {
  if (threadIdx.x == 0 && blockIdx.x == 0) {
    int s = 0, yt = 0;
    ctrl[CTRL_SEG] = 0;
    for (int e = 0; e < N_EXP; ++e) {
      const int c = ctrl[CTRL_COUNT + e];
      const int padded = (c + 255) & ~255;
      const int n = padded >> 8;
      for (int j = 0; j < n; ++j) ctrl[CTRL_YT + yt + j] = e;
      yt += n;
      s += padded;
      ctrl[CTRL_SEG + 1 + e] = s;
    }
    for (; yt < NYT; ++yt) ctrl[CTRL_YT + yt] = -1;
  }
}

// ---------------- scatter ----------------
__global__ void scatter_kernel(const int* __restrict__ topidx, const float* __restrict__ topw,
                               int* __restrict__ ctrl, int* __restrict__ rowmap,
                               float* __restrict__ roww) {
  const int t = blockIdx.x * blockDim.x + threadIdx.x;
  if (t >= T_TOKENS) return;
#pragma unroll
  for (int k = 0; k < 2; ++k) {
    const int e = topidx[t * 2 + k];
    const int pos = ctrl[CTRL_SEG + e] + atomicAdd(&ctrl[CTRL_CUR + e], 1);
    rowmap[pos] = t * 2 + k;
    roww[pos] = topw[t * 2 + k];
  }
}

// =====================================================================
// GEMM1 (round-5 verified core): 256x256, BK=64 split in 2 K-halves of 32,
// 2 LDS slots, 4 phases per K-tile, VMW(8) never-0.  Chunk swizzle:
// logical k-chunk kc of row r at physical (kc+(r>>1))&3 within each half.
//   PH1(t): read kh0 A+Blo   stage A-kh1(t+1)->slot^1
//   PH2(t): read kh0 Bhi     stage B-kh1(t+1)->slot^1   VMW(8)
//   PH3(t): read kh1 A+Blo   stage A-kh0(t+2)->slot
//   PH4(t): read kh1 Bhi     stage B-kh0(t+2)->slot     VMW(8)
// Grid compacted: 72 ytiles x 22 xn = 1584 blocks; XCD-clustered.
// =====================================================================
__global__ void __launch_bounds__(512, 2) gemm1_kernel(
    const __hip_bfloat16* __restrict__ xb,
    const __hip_bfloat16* __restrict__ wcat,
    __hip_bfloat16* __restrict__ H,
    const int* __restrict__ rowmap, const float* __restrict__ roww,
    const int* __restrict__ ctrl) {
  const unsigned b = blockIdx.x;       // 1584 blocks
  const int xcd = b & 7;
  const unsigned w = b >> 3;           // 0..197
  const int yt = xcd * 9 + (int)(w % 9);
  const int xn = (int)(w / 9);         // 0..21
  const int e = ctrl[CTRL_YT + yt];
  if (e < 0) return;
  const int row0 = yt * 256;
  const int nbase = xn * 256;
  const int tid = threadIdx.x, lane = tid & 63, wid = tid >> 6;
  const int wrm = (wid >> 2) * 128, wrn = (wid & 3) * 64;

  __shared__ __align__(16) __hip_bfloat16 sA[2][2][8192];
  __shared__ __align__(16) __hip_bfloat16 sB[2][2][8192];
  __shared__ float sW[256];

  if (tid < 256) sW[tid] = roww[row0 + tid];

  const int srow = tid >> 2;
  const int kc = ((tid & 3) - ((tid >> 3) & 3)) & 3;   // inverse swizzle on source
  int tok0 = rowmap[row0 + srow] >> 1;
  int tok1 = rowmap[row0 + 128 + srow] >> 1;
  tok0 = min(tok0, T_TOKENS - 1);   // pads -> any valid row; sW=0 zeroes H
  tok1 = min(tok1, T_TOKENS - 1);
  const __hip_bfloat16* gA0 = xb + (size_t)tok0 * D_MODEL + kc * 8;
  const __hip_bfloat16* gA1 = xb + (size_t)tok1 * D_MODEL + kc * 8;
  const __hip_bfloat16* gB0 = wcat + ((size_t)e * N_CAT + nbase + srow) * D_MODEL + kc * 8;
  const __hip_bfloat16* gB1 = gB0 + (size_t)128 * D_MODEL;

  __syncthreads();   // sW visible; drains all loads so vmcnt counting starts at 0

  auto stageA = [&](int sl_, int kh, int kt) {
    const int ko = kt * 64 + kh * 32;
    gll16(gA0 + ko, &sA[sl_][kh][tid * 8]);
    gll16(gA1 + ko, &sA[sl_][kh][4096 + tid * 8]);
  };
  auto stageB = [&](int sl_, int kh, int kt) {
    const int ko = kt * 64 + kh * 32;
    gll16(gB0 + ko, &sB[sl_][kh][tid * 8]);
    gll16(gB1 + ko, &sB[sl_][kh][4096 + tid * 8]);
  };

  f32x4 acc[8][4];
  const f32x4 z4 = {0.f, 0.f, 0.f, 0.f};
#pragma unroll
  for (int a_ = 0; a_ < 8; ++a_)
#pragma unroll
    for (int b_ = 0; b_ < 4; ++b_) acc[a_][b_] = z4;

  const int poff = ((lane >> 4) + ((lane & 15) >> 1)) & 3;
  const int arow = (wrm + (lane & 15)) * 32 + poff * 8;
  const int brow = (wrn + (lane & 15)) * 32 + poff * 8;

  const int NT = D_MODEL / 64;   // 16
  stageA(0, 0, 0); stageB(0, 0, 0);
  stageA(0, 1, 0); stageB(0, 1, 0);
  stageA(1, 0, 1); stageB(1, 0, 1);
  VMW("8"); BARRIER();

  for (int t = 0; t < NT; ++t) {
    const int sl = t & 1;
    const int tn1 = (t + 1 < NT) ? t + 1 : 0;
    const int tn2 = (t + 2 < NT) ? t + 2 : 0;
    bf16x8 af[8], bf0[2], bf1[2];
    // ---- PH1 ----
#pragma unroll
    for (int mi = 0; mi < 8; ++mi) af[mi] = *(const bf16x8*)&sA[sl][0][arow + mi * 512];
#pragma unroll
    for (int j = 0; j < 2; ++j) bf0[j] = *(const bf16x8*)&sB[sl][0][brow + j * 512];
    stageA(sl ^ 1, 1, tn1);
    BARRIER();
    __builtin_amdgcn_s_setprio(1);
#pragma unroll
    for (int mi = 0; mi < 8; ++mi)
#pragma unroll
      for (int j = 0; j < 2; ++j)
        acc[mi][j] = __builtin_amdgcn_mfma_f32_16x16x32_bf16(af[mi], bf0[j], acc[mi][j], 0, 0, 0);
    __builtin_amdgcn_s_setprio(0);
    BARRIER();
    // ---- PH2 ----
#pragma unroll
    for (int j = 0; j < 2; ++j) bf1[j] = *(const bf16x8*)&sB[sl][0][brow + (2 + j) * 512];
    stageB(sl ^ 1, 1, tn1);
    VMW("8");
    BARRIER();
    __builtin_amdgcn_s_setprio(1);
#pragma unroll
    for (int mi = 0; mi < 8; ++mi)
#pragma unroll
      for (int j = 0; j < 2; ++j)
        acc[mi][2 + j] = __builtin_amdgcn_mfma_f32_16x16x32_bf16(af[mi], bf1[j], acc[mi][2 + j], 0, 0, 0);
    __builtin_amdgcn_s_setprio(0);
    BARRIER();
    // ---- PH3 ----
#pragma unroll
    for (int mi = 0; mi < 8; ++mi) af[mi] = *(const bf16x8*)&sA[sl][1][arow + mi * 512];
#pragma unroll
    for (int j = 0; j < 2; ++j) bf0[j] = *(const bf16x8*)&sB[sl][1][brow + j * 512];
    stageA(sl, 0, tn2);
    BARRIER();
    __builtin_amdgcn_s_setprio(1);
#pragma unroll
    for (int mi = 0; mi < 8; ++mi)
#pragma unroll
      for (int j = 0; j < 2; ++j)
        acc[mi][j] = __builtin_amdgcn_mfma_f32_16x16x32_bf16(af[mi], bf0[j], acc[mi][j], 0, 0, 0);
    __builtin_amdgcn_s_setprio(0);
    BARRIER();
    // ---- PH4 ----
#pragma unroll
    for (int j = 0; j < 2; ++j) bf1[j] = *(const bf16x8*)&sB[sl][1][brow + (2 + j) * 512];
    stageB(sl, 0, tn2);
    VMW("8");
    BARRIER();
    __builtin_amdgcn_s_setprio(1);
#pragma unroll
    for (int mi = 0; mi < 8; ++mi)
#pragma unroll
      for (int j = 0; j < 2; ++j)
        acc[mi][2 + j] = __builtin_amdgcn_mfma_f32_16x16x32_bf16(af[mi], bf1[j], acc[mi][2 + j], 0, 0, 0);
    __builtin_amdgcn_s_setprio(0);
    BARRIER();
  }

  // epilogue: pair gate (ni 0,1) with up (ni 2,3); pre-scale by routing weight
  const int hcolbase = ((nbase + wrn) >> 6) * 32;
#pragma unroll
  for (int mi = 0; mi < 8; ++mi) {
    const int r0 = wrm + mi * 16 + ((lane >> 4) * 4);
#pragma unroll
    for (int ni = 0; ni < 2; ++ni) {
      const int hcol = hcolbase + ni * 16 + (lane & 15);
      const f32x4 g = acc[mi][ni], u = acc[mi][ni + 2];
#pragma unroll
      for (int j = 0; j < 4; ++j) {
        const float h = silu_mul(g[j], u[j]) * sW[r0 + j];
        H[(size_t)(row0 + r0 + j) * I_PAD + hcol] = __float2bfloat16(h);
      }
    }
  }
}

// =====================================================================
// GEMM2 (m97 anatomy): 128x128 tile, 4 waves, BK=64, single-buffer
// 2-barrier loop, 3 blocks/CU (cross-block overlap hides vmcnt drains).
// LDS [128][64] with chunk swizzle p=(kc+row)&7 -> each 16-lane read
// phase hits 8 bank-quads x 2 lanes (free).  slot-store epilogue.
// Grid: 144 mtiles x 8 n = 1152; XCD-clustered (18 mtiles/XCD).
// =====================================================================
__global__ void __launch_bounds__(256, 3) gemm2_kernel(
    const __hip_bfloat16* __restrict__ H,
    const __hip_bfloat16* __restrict__ wdt,   // [E][D][I_PAD] n-major
    ushort_t* __restrict__ slot,              // [2T+1][D] bf16 bits
    const int* __restrict__ rowmap, const int* __restrict__ ctrl) {
  const unsigned b = blockIdx.x;       // 1152 blocks
  const int xcd = b & 7;
  const unsigned w = b >> 3;           // 0..143
  const int mt = xcd * 18 + (int)(w % 18);   // 0..143
  const int xn = (int)(w / 18);        // 0..7
  const int e = ctrl[CTRL_YT + (mt >> 1)];
  if (e < 0) return;
  const int row0 = mt * 128;
  const int nbase = xn * 128;
  const int tid = threadIdx.x, lane = tid & 63, wid = tid >> 6;
  const int wr = (wid >> 1) * 64, wc = (wid & 1) * 64;

  __shared__ __align__(16) __hip_bfloat16 sA[128 * 64];
  __shared__ __align__(16) __hip_bfloat16 sB[128 * 64];
  __shared__ int sTok[128];

  if (tid < 128) sTok[tid] = rowmap[row0 + tid];

  // staging: 4 chunks/thread/array; chunk c = i*256+tid -> row=c>>3, phys pc=c&7,
  // logical kc8 = (pc - row) & 7 (inverse of p=(kc+row)&7)
  const __hip_bfloat16* gA[4];
  const __hip_bfloat16* gB[4];
#pragma unroll
  for (int i = 0; i < 4; ++i) {
    const int c = i * 256 + tid;
    const int row = c >> 3;
    const int kc8 = ((c & 7) - row) & 7;
    gA[i] = H + (size_t)(row0 + row) * I_PAD + kc8 * 8;
    gB[i] = wdt + ((size_t)e * D_MODEL + nbase + row) * I_PAD + kc8 * 8;
  }

  f32x4 acc[4][4];
  const f32x4 z4 = {0.f, 0.f, 0.f, 0.f};
#pragma unroll
  for (int a_ = 0; a_ < 4; ++a_)
#pragma unroll
    for (int b_ = 0; b_ < 4; ++b_) acc[a_][b_] = z4;

  const int NT = I_PAD / 64;   // 44
  for (int kt = 0; kt < NT; ++kt) {
    __syncthreads();    // prior reads of sA/sB complete (and sTok on iter 0)
#pragma unroll
    for (int i = 0; i < 4; ++i) {
      const int c = i * 256 + tid;
      gll16(gA[i] + kt * 64, &sA[c * 8]);
      gll16(gB[i] + kt * 64, &sB[c * 8]);
    }
    __syncthreads();    // compiler drains vmcnt(0) before barrier -> data ready
#pragma unroll
    for (int ks = 0; ks < 2; ++ks) {
      bf16x8 a[4], bb[4];
#pragma unroll
      for (int mi = 0; mi < 4; ++mi) {
        const int row = wr + mi * 16 + (lane & 15);
        const int p = (ks * 4 + (lane >> 4) + row) & 7;
        a[mi] = *(const bf16x8*)&sA[row * 64 + p * 8];
      }
#pragma unroll
      for (int ni = 0; ni < 4; ++ni) {
        const int row = wc + ni * 16 + (lane & 15);
        const int p = (ks * 4 + (lane >> 4) + row) & 7;
        bb[ni] = *(const bf16x8*)&sB[row * 64 + p * 8];
      }
      __builtin_amdgcn_s_setprio(1);
#pragma unroll
      for (int mi = 0; mi < 4; ++mi)
#pragma unroll
        for (int ni = 0; ni < 4; ++ni)
          acc[mi][ni] = __builtin_amdgcn_mfma_f32_16x16x32_bf16(a[mi], bb[ni], acc[mi][ni], 0, 0, 0);
      __builtin_amdgcn_s_setprio(0);
    }
  }

#pragma unroll
  for (int mi = 0; mi < 4; ++mi) {
    const int r0 = wr + mi * 16 + ((lane >> 4) * 4);
#pragma unroll
    for (int ni = 0; ni < 4; ++ni) {
      const int col = nbase + wc + ni * 16 + (lane & 15);
#pragma unroll
      for (int j = 0; j < 4; ++j) {
        const int sid = sTok[r0 + j];
        __hip_bfloat16 hv = __float2bfloat16(acc[mi][ni][j]);
        slot[(size_t)sid * D_MODEL + col] = *(const ushort_t*)&hv;
      }
    }
  }
}

// ---------------- combine: out[t] = slot[2t] + slot[2t+1] ----------------
__global__ void __launch_bounds__(256) combine_kernel(
    const ushort_t* __restrict__ slot, float* __restrict__ out) {
  const int i = blockIdx.x * 256 + threadIdx.x;   // over T*D/8
  const int t = i >> 7;
  const int c = (i & 127) << 3;
  const size_t b0 = ((size_t)(t << 1)) * D_MODEL + c;
  const ushort8 a = *(const ushort8*)&slot[b0];
  const ushort8 b = *(const ushort8*)&slot[b0 + D_MODEL];
  float4 o0, o1;
  o0.x = bf2f(a[0]) + bf2f(b[0]); o0.y = bf2f(a[1]) + bf2f(b[1]);
  o0.z = bf2f(a[2]) + bf2f(b[2]); o0.w = bf2f(a[3]) + bf2f(b[3]);
  o1.x = bf2f(a[4]) + bf2f(b[4]); o1.y = bf2f(a[5]) + bf2f(b[5]);
  o1.z = bf2f(a[6]) + bf2f(b[6]); o1.w = bf2f(a[7]) + bf2f(b[7]);
  ((float4*)out)[i * 2] = o0;
  ((float4*)out)[i * 2 + 1] = o1;
}

// ---------------- launch ----------------
extern "C" void kernel_launch(void* const* d_in, const int* in_sizes, int n_in,
                              void* d_out, int out_size, void* d_ws, size_t ws_size,
                              hipStream_t stream) {
  (void)in_sizes; (void)n_in; (void)ws_size; (void)out_size;
  const float* x  = (const float*)d_in[0];
  const float* rw = (const float*)d_in[1];
  const float* wg = (const float*)d_in[2];
  const float* wu = (const float*)d_in[3];
  const float* wd = (const float*)d_in[4];
  float* out = (float*)d_out;

  char* ws = (char*)d_ws;
  size_t off = 0;
  auto alloc = [&](size_t bytes) -> char* {
    char* p = ws + off;
    off += (bytes + 255) & ~(size_t)255;
    return p;
  };

  int*   ctrl   = (int*)alloc(512);
  int*   topidx = (int*)alloc((size_t)T_TOKENS * 2 * 4);
  float* topw   = (float*)alloc((size_t)T_TOKENS * 2 * 4);
  int*   rowmap = (int*)alloc((size_t)MAXROWS * 4);
  float* roww   = (float*)alloc((size_t)MAXROWS * 4);
  __hip_bfloat16* xb   = (__hip_bfloat16*)alloc((size_t)T_TOKENS * D_MODEL * 2);
  __hip_bfloat16* wcat = (__hip_bfloat16*)alloc((size_t)N_EXP * N_CAT * D_MODEL * 2);
  __hip_bfloat16* Hbuf = (__hip_bfloat16*)alloc((size_t)MAXROWS * I_PAD * 2);
  ushort_t* slotout = (ushort_t*)alloc((size_t)(2 * T_TOKENS + 1) * D_MODEL * 2);
  // wdt aliases wcat (wcat dead after gemm1; wdt transpose runs after gemm1)
  __hip_bfloat16* wdt = wcat;

  hipMemsetAsync(ctrl, 0, 256, stream);

  cvt_x_kernel<<<(T_TOKENS * D_MODEL / 4 + 255) / 256, 256, 0, stream>>>(
      x, xb, T_TOKENS * D_MODEL / 4);

  // wg [E][1024][2752] -> wcat gate rows; wu -> wcat up rows
  transpose_cvt_kernel<<<dim3(D_MODEL / 64, I_PAD / 64, N_EXP), 256, 0, stream>>>(
      wg, wcat, D_MODEL, I_RAW, D_MODEL, (long)D_MODEL * I_RAW, (long)N_CAT * D_MODEL, 1);
  transpose_cvt_kernel<<<dim3(D_MODEL / 64, I_PAD / 64, N_EXP), 256, 0, stream>>>(
      wu, wcat, D_MODEL, I_RAW, D_MODEL, (long)D_MODEL * I_RAW, (long)N_CAT * D_MODEL, 2);

  router_kernel<<<T_TOKENS, 64, 0, stream>>>(x, rw, topidx, topw, ctrl);
  padfill_kernel<<<(MAXROWS + 255) / 256, 256, 0, stream>>>(rowmap, roww);
  scan_kernel<<<1, 64, 0, stream>>>(ctrl);
  scatter_kernel<<<(T_TOKENS + 255) / 256, 256, 0, stream>>>(topidx, topw, ctrl, rowmap, roww);

  gemm1_kernel<<<dim3(NYT * 22), 512, 0, stream>>>(
      xb, wcat, Hbuf, rowmap, roww, ctrl);

  // wd [E][2752][1024] -> wdt [E][1024][2816]  (into wcat's space, after gemm1)
  transpose_cvt_kernel<<<dim3(I_PAD / 64, D_MODEL / 64, N_EXP), 256, 0, stream>>>(
      wd, wdt, I_RAW, D_MODEL, I_PAD, (long)I_RAW * D_MODEL, (long)D_MODEL * I_PAD, 0);

  gemm2_kernel<<<dim3(NYT * 2 * 8), 256, 0, stream>>>(
      Hbuf, wdt, slotout, rowmap, ctrl);

  combine_kernel<<<(T_TOKENS * D_MODEL / 8) / 256, 256, 0, stream>>>(slotout, out);
}

// Round 8
// 515.744 us; speedup vs baseline: 3.8683x; 1.4989x over previous
//
#include <hip/hip_runtime.h>
#include <hip/hip_bf16.h>
#include <math.h>

// ---------------- problem constants ----------------
#define T_TOKENS 8192          // B*S = 4*2048
#define D_MODEL  1024
#define N_EXP    8
#define I_RAW    2752
#define I_PAD    2816          // 88 * 32
#define N_CAT    5632          // 2 * I_PAD (gate/up interleaved in 32-blocks)
#define MAXROWS  18432         // 72 * 256 >= 16384 + 8*255
#define NYT      72
#define DUMP_SID (2 * T_TOKENS)

typedef __attribute__((ext_vector_type(8))) short bf16x8;
typedef __attribute__((ext_vector_type(8))) unsigned short ushort8;
typedef __attribute__((ext_vector_type(4))) float f32x4;
typedef unsigned short ushort_t;

// ctrl layout (ints): [0..7] counts, [8..15] cursor, [16..24] seg offsets,
// [32..103] ytile -> expert table (-1 = inactive)
#define CTRL_COUNT 0
#define CTRL_CUR   8
#define CTRL_SEG   16
#define CTRL_YT    32

#define VMW(n)  asm volatile("s_waitcnt vmcnt(" n ")" ::: "memory")
#define BARRIER() asm volatile("s_barrier" ::: "memory")

__device__ __forceinline__ void gll16(const void* g, void* l) {
  __builtin_amdgcn_global_load_lds(
      (const __attribute__((address_space(1))) void*)g,
      (__attribute__((address_space(3))) void*)l, 16, 0, 0);
}

__device__ __forceinline__ float silu_mul(float g, float u) {
  return g / (1.f + __expf(-g)) * u;
}

__device__ __forceinline__ float bf2f(ushort_t u) {
  return __uint_as_float((unsigned)u << 16);
}

// ---------------- router: one wave per token (no atomics) ----------------
__global__ void __launch_bounds__(64) router_kernel(
    const float* __restrict__ x, const float* __restrict__ rw,
    int* __restrict__ topidx, float* __restrict__ topw) {
  const int t = blockIdx.x;
  const int lane = threadIdx.x;
  const float* xr = x + (size_t)t * D_MODEL;
  float acc[N_EXP];
#pragma unroll
  for (int e = 0; e < N_EXP; ++e) acc[e] = 0.f;
  for (int d = lane; d < D_MODEL; d += 64) {
    const float xv = xr[d];
    const float* r = rw + (size_t)d * N_EXP;
#pragma unroll
    for (int e = 0; e < N_EXP; ++e) acc[e] = fmaf(xv, r[e], acc[e]);
  }
#pragma unroll
  for (int e = 0; e < N_EXP; ++e) {
    for (int off = 32; off > 0; off >>= 1) acc[e] += __shfl_xor(acc[e], off, 64);
  }
  if (lane == 0) {
    float m = acc[0];
#pragma unroll
    for (int e = 1; e < N_EXP; ++e) m = fmaxf(m, acc[e]);
    float p[N_EXP], s = 0.f;
#pragma unroll
    for (int e = 0; e < N_EXP; ++e) { p[e] = expf(acc[e] - m); s += p[e]; }
    int i0 = 0; float v0 = p[0];
#pragma unroll
    for (int e = 1; e < N_EXP; ++e) if (p[e] > v0) { v0 = p[e]; i0 = e; }
    int i1 = -1; float v1 = -1.f;
#pragma unroll
    for (int e = 0; e < N_EXP; ++e) if (e != i0 && p[e] > v1) { v1 = p[e]; i1 = e; }
    v0 /= s; v1 /= s;
    const float r = v0 + v1 + 1e-6f;
    v0 /= r; v1 /= r;
    topidx[t * 2] = i0; topidx[t * 2 + 1] = i1;
    topw[t * 2] = v0;  topw[t * 2 + 1] = v1;
  }
}

// ---------------- histogram: counts via LDS (256 global atomics total) -------
__global__ void __launch_bounds__(512) hist_kernel(
    const int* __restrict__ topidx, int* __restrict__ ctrl) {
  __shared__ int lh[N_EXP];
  const int tid = threadIdx.x;
  if (tid < N_EXP) lh[tid] = 0;
  __syncthreads();
  const int g = blockIdx.x * 512 + tid;      // over 2T = 16384 slots
  atomicAdd(&lh[topidx[g]], 1);
  __syncthreads();
  if (tid < N_EXP) atomicAdd(&ctrl[CTRL_COUNT + tid], lh[tid]);
}

// ---------------- x -> bf16 ----------------
__global__ void cvt_x_kernel(const float* __restrict__ x,
                             __hip_bfloat16* __restrict__ xb, int n4) {
  const int i = blockIdx.x * blockDim.x + threadIdx.x;
  if (i < n4) {
    const float4 v = ((const float4*)x)[i];
    __hip_bfloat16 b0 = __float2bfloat16(v.x), b1 = __float2bfloat16(v.y);
    __hip_bfloat16 b2 = __float2bfloat16(v.z), b3 = __float2bfloat16(v.w);
    ushort4 o;
    o.x = reinterpret_cast<ushort_t&>(b0); o.y = reinterpret_cast<ushort_t&>(b1);
    o.z = reinterpret_cast<ushort_t&>(b2); o.w = reinterpret_cast<ushort_t&>(b3);
    ((ushort4*)xb)[i] = o;
  }
}

// ---------------- transpose + convert, 64x64 tiles, vectorized ----------------
__global__ void __launch_bounds__(256) transpose_cvt_kernel(
    const float* __restrict__ in, __hip_bfloat16* __restrict__ out,
    int Rin, int Cin, int Co, long in_es, long out_es, int mode) {
  __shared__ float tile[64][65];
  const float* inp = in + (size_t)blockIdx.z * in_es;
  __hip_bfloat16* outp = out + (size_t)blockIdx.z * out_es;
  const int b0 = blockIdx.x * 64;   // input-row / out-col tile
  const int a0 = blockIdx.y * 64;   // input-col / out-row tile
  const int tid = threadIdx.x;
  const bool inb = (b0 < Rin) && (a0 < Cin);
  const int bi0 = tid >> 4, a4 = (tid & 15) * 4;
  if (inb) {
#pragma unroll
    for (int i = 0; i < 4; ++i) {
      const int bi = bi0 + i * 16;
      const float4 v = *(const float4*)&inp[(size_t)(b0 + bi) * Cin + a0 + a4];
      tile[bi][a4] = v.x; tile[bi][a4 + 1] = v.y;
      tile[bi][a4 + 2] = v.z; tile[bi][a4 + 3] = v.w;
    }
  } else {
#pragma unroll
    for (int i = 0; i < 4; ++i) {
      const int bi = bi0 + i * 16;
      tile[bi][a4] = 0.f; tile[bi][a4 + 1] = 0.f;
      tile[bi][a4 + 2] = 0.f; tile[bi][a4 + 3] = 0.f;
    }
  }
  __syncthreads();
#pragma unroll
  for (int half = 0; half < 2; ++half) {
    const int g = tid + half * 256;
    const int al = g >> 3, bc = (g & 7) * 8;
    ushort8 o;
#pragma unroll
    for (int j = 0; j < 8; ++j) {
      __hip_bfloat16 h = __float2bfloat16(tile[bc + j][al]);
      o[j] = *(const ushort_t*)&h;
    }
    const int a = a0 + al;
    int A;
    if (mode == 0) A = a;
    else A = ((a >> 5) << 6) + ((mode == 2) ? 32 : 0) + (a & 31);
    *(ushort8*)&outp[(size_t)A * Co + b0 + bc] = o;
  }
}

// ---------------- pad fill: pads point at the dump slot ----------------
__global__ void padfill_kernel(int* __restrict__ rowmap, float* __restrict__ roww) {
  const int i = blockIdx.x * blockDim.x + threadIdx.x;
  if (i < MAXROWS) { rowmap[i] = DUMP_SID; roww[i] = 0.f; }
}

// ---------------- scan: seg offsets + ytile table ----------------
__global__ void scan_kernel(int* __restrict__ ctrl) {
  if (threadIdx.x == 0 && blockIdx.x == 0) {
    int s = 0, yt = 0;
    ctrl[CTRL_SEG] = 0;
    for (int e = 0; e < N_EXP; ++e) {
      const int c = ctrl[CTRL_COUNT + e];
      const int padded = (c + 255) & ~255;
      const int n = padded >> 8;
      for (int j = 0; j < n; ++j) ctrl[CTRL_YT + yt + j] = e;
      yt += n;
      s += padded;
      ctrl[CTRL_SEG + 1 + e] = s;
    }
    for (; yt < NYT; ++yt) ctrl[CTRL_YT + yt] = -1;
  }
}

// ---------------- scatter: LDS rank + one global atomic per expert/block ----
__global__ void __launch_bounds__(512) scatter_kernel(
    const int* __restrict__ topidx, const float* __restrict__ topw,
    int* __restrict__ ctrl, int* __restrict__ rowmap,
    float* __restrict__ roww) {
  __shared__ int lh[N_EXP];
  __shared__ int lbase[N_EXP];
  const int tid = threadIdx.x;
  if (tid < N_EXP) lh[tid] = 0;
  __syncthreads();
  const int g = blockIdx.x * 512 + tid;      // slot id
  const int e = topidx[g];
  const int rank = atomicAdd(&lh[e], 1);
  __syncthreads();
  if (tid < N_EXP) lbase[tid] = atomicAdd(&ctrl[CTRL_CUR + tid], lh[tid]);
  __syncthreads();
  const int pos = ctrl[CTRL_SEG + e] + lbase[e] + rank;
  rowmap[pos] = g;
  roww[pos] = topw[g];
}

// =====================================================================
// GEMM1: 256x256, BK=64 split in 2 K-halves of 32, 2 LDS slots,
// 4 phases/K-tile, VMW(8) never-0 (verified schedule).  This round:
// K-loop unrolled x2 (slot index compile-time) and even ds_read split
// (PH1: aLo+B = 8 b128, PH2: aHi = 4, PH3: 8, PH4: 4).
// Chunk swizzle: logical kc of row r at physical (kc+(r>>1))&3 per half.
// Grid compacted: 72 ytiles x 22 xn = 1584 blocks; XCD-clustered.
// =====================================================================
__global__ void __launch_bounds__(512, 2) gemm1_kernel(
    const __hip_bfloat16* __restrict__ xb,
    const __hip_bfloat16* __restrict__ wcat,
    __hip_bfloat16* __restrict__ H,
    const int* __restrict__ rowmap, const float* __restrict__ roww,
    const int* __restrict__ ctrl) {
  const unsigned b = blockIdx.x;       // 1584 blocks
  const int xcd = b & 7;
  const unsigned w = b >> 3;           // 0..197
  const int yt = xcd * 9 + (int)(w % 9);
  const int xn = (int)(w / 9);         // 0..21
  const int e = ctrl[CTRL_YT + yt];
  if (e < 0) return;
  const int row0 = yt * 256;
  const int nbase = xn * 256;
  const int tid = threadIdx.x, lane = tid & 63, wid = tid >> 6;
  const int wrm = (wid >> 2) * 128, wrn = (wid & 3) * 64;

  __shared__ __align__(16) __hip_bfloat16 sA[2][2][8192];
  __shared__ __align__(16) __hip_bfloat16 sB[2][2][8192];
  __shared__ float sW[256];

  if (tid < 256) sW[tid] = roww[row0 + tid];

  const int srow = tid >> 2;
  const int kc = ((tid & 3) - ((tid >> 3) & 3)) & 3;   // inverse swizzle on source
  int tok0 = rowmap[row0 + srow] >> 1;
  int tok1 = rowmap[row0 + 128 + srow] >> 1;
  tok0 = min(tok0, T_TOKENS - 1);   // pads -> any valid row; sW=0 zeroes H
  tok1 = min(tok1, T_TOKENS - 1);
  const __hip_bfloat16* gA0 = xb + (size_t)tok0 * D_MODEL + kc * 8;
  const __hip_bfloat16* gA1 = xb + (size_t)tok1 * D_MODEL + kc * 8;
  const __hip_bfloat16* gB0 = wcat + ((size_t)e * N_CAT + nbase + srow) * D_MODEL + kc * 8;
  const __hip_bfloat16* gB1 = gB0 + (size_t)128 * D_MODEL;

  __syncthreads();   // sW visible; drains all loads so vmcnt counting starts at 0

  auto stageA = [&](int sl_, int kh, int kt) {
    const int ko = kt * 64 + kh * 32;
    gll16(gA0 + ko, &sA[sl_][kh][tid * 8]);
    gll16(gA1 + ko, &sA[sl_][kh][4096 + tid * 8]);
  };
  auto stageB = [&](int sl_, int kh, int kt) {
    const int ko = kt * 64 + kh * 32;
    gll16(gB0 + ko, &sB[sl_][kh][tid * 8]);
    gll16(gB1 + ko, &sB[sl_][kh][4096 + tid * 8]);
  };

  f32x4 acc[8][4];
  const f32x4 z4 = {0.f, 0.f, 0.f, 0.f};
#pragma unroll
  for (int a_ = 0; a_ < 8; ++a_)
#pragma unroll
    for (int b_ = 0; b_ < 4; ++b_) acc[a_][b_] = z4;

  const int poff = ((lane >> 4) + ((lane & 15) >> 1)) & 3;
  const int arow = (wrm + (lane & 15)) * 32 + poff * 8;
  const int brow = (wrn + (lane & 15)) * 32 + poff * 8;

  const int NT = D_MODEL / 64;   // 16
  stageA(0, 0, 0); stageB(0, 0, 0);
  stageA(0, 1, 0); stageB(0, 1, 0);
  stageA(1, 0, 1); stageB(1, 0, 1);
  VMW("8"); BARRIER();

#define G1_HALF(SL, KH, T, STG_A, STG_B)                                       \
  {                                                                            \
    bf16x8 aLo[4], aHi[4], bfv[4];                                             \
    _Pragma("unroll")                                                          \
    for (int mi = 0; mi < 4; ++mi)                                             \
      aLo[mi] = *(const bf16x8*)&sA[SL][KH][arow + mi * 512];                  \
    _Pragma("unroll")                                                          \
    for (int ni = 0; ni < 4; ++ni)                                             \
      bfv[ni] = *(const bf16x8*)&sB[SL][KH][brow + ni * 512];                  \
    STG_A;                                                                     \
    BARRIER();                                                                 \
    __builtin_amdgcn_s_setprio(1);                                             \
    _Pragma("unroll")                                                          \
    for (int mi = 0; mi < 4; ++mi)                                             \
      _Pragma("unroll")                                                        \
      for (int ni = 0; ni < 4; ++ni)                                           \
        acc[mi][ni] = __builtin_amdgcn_mfma_f32_16x16x32_bf16(aLo[mi], bfv[ni], acc[mi][ni], 0, 0, 0); \
    __builtin_amdgcn_s_setprio(0);                                             \
    BARRIER();                                                                 \
    _Pragma("unroll")                                                          \
    for (int mi = 0; mi < 4; ++mi)                                             \
      aHi[mi] = *(const bf16x8*)&sA[SL][KH][arow + (4 + mi) * 512];            \
    STG_B;                                                                     \
    VMW("8");                                                                  \
    BARRIER();                                                                 \
    __builtin_amdgcn_s_setprio(1);                                             \
    _Pragma("unroll")                                                          \
    for (int mi = 0; mi < 4; ++mi)                                             \
      _Pragma("unroll")                                                        \
      for (int ni = 0; ni < 4; ++ni)                                           \
        acc[4 + mi][ni] = __builtin_amdgcn_mfma_f32_16x16x32_bf16(aHi[mi], bfv[ni], acc[4 + mi][ni], 0, 0, 0); \
    __builtin_amdgcn_s_setprio(0);                                             \
    BARRIER();                                                                 \
  }

#define G1_KTILE(SL, T)                                                        \
  {                                                                            \
    const int tn1 = ((T) + 1 < NT) ? (T) + 1 : 0;                              \
    const int tn2 = ((T) + 2 < NT) ? (T) + 2 : 0;                              \
    G1_HALF(SL, 0, T, stageA(1 - (SL), 1, tn1), stageB(1 - (SL), 1, tn1))      \
    G1_HALF(SL, 1, T, stageA((SL), 0, tn2),     stageB((SL), 0, tn2))          \
  }

  for (int t = 0; t < NT; t += 2) {
    G1_KTILE(0, t)
    G1_KTILE(1, t + 1)
  }

  // epilogue: pair gate (ni 0,1) with up (ni 2,3); pre-scale by routing weight
  const int hcolbase = ((nbase + wrn) >> 6) * 32;
#pragma unroll
  for (int mi = 0; mi < 8; ++mi) {
    const int r0 = wrm + mi * 16 + ((lane >> 4) * 4);
#pragma unroll
    for (int ni = 0; ni < 2; ++ni) {
      const int hcol = hcolbase + ni * 16 + (lane & 15);
      const f32x4 g = acc[mi][ni], u = acc[mi][ni + 2];
#pragma unroll
      for (int j = 0; j < 4; ++j) {
        const float h = silu_mul(g[j], u[j]) * sW[r0 + j];
        H[(size_t)(row0 + r0 + j) * I_PAD + hcol] = __float2bfloat16(h);
      }
    }
  }
}

// =====================================================================
// GEMM2 (m97 anatomy): 128x128 tile, 4 waves, BK=64, single-buffer
// 2-barrier loop, 3 blocks/CU.  LDS chunk swizzle p=(kc+row)&7.
// Grid: 144 mtiles x 8 n = 1152; XCD-clustered (18 mtiles/XCD).
// =====================================================================
__global__ void __launch_bounds__(256, 3) gemm2_kernel(
    const __hip_bfloat16* __restrict__ H,
    const __hip_bfloat16* __restrict__ wdt,   // [E][D][I_PAD] n-major
    ushort_t* __restrict__ slot,              // [2T+1][D] bf16 bits
    const int* __restrict__ rowmap, const int* __restrict__ ctrl) {
  const unsigned b = blockIdx.x;       // 1152 blocks
  const int xcd = b & 7;
  const unsigned w = b >> 3;           // 0..143
  const int mt = xcd * 18 + (int)(w % 18);   // 0..143
  const int xn = (int)(w / 18);        // 0..7
  const int e = ctrl[CTRL_YT + (mt >> 1)];
  if (e < 0) return;
  const int row0 = mt * 128;
  const int nbase = xn * 128;
  const int tid = threadIdx.x, lane = tid & 63, wid = tid >> 6;
  const int wr = (wid >> 1) * 64, wc = (wid & 1) * 64;

  __shared__ __align__(16) __hip_bfloat16 sA[128 * 64];
  __shared__ __align__(16) __hip_bfloat16 sB[128 * 64];
  __shared__ int sTok[128];

  if (tid < 128) sTok[tid] = rowmap[row0 + tid];

  const __hip_bfloat16* gA[4];
  const __hip_bfloat16* gB[4];
#pragma unroll
  for (int i = 0; i < 4; ++i) {
    const int c = i * 256 + tid;
    const int row = c >> 3;
    const int kc8 = ((c & 7) - row) & 7;
    gA[i] = H + (size_t)(row0 + row) * I_PAD + kc8 * 8;
    gB[i] = wdt + ((size_t)e * D_MODEL + nbase + row) * I_PAD + kc8 * 8;
  }

  f32x4 acc[4][4];
  const f32x4 z4 = {0.f, 0.f, 0.f, 0.f};
#pragma unroll
  for (int a_ = 0; a_ < 4; ++a_)
#pragma unroll
    for (int b_ = 0; b_ < 4; ++b_) acc[a_][b_] = z4;

  const int NT = I_PAD / 64;   // 44
  for (int kt = 0; kt < NT; ++kt) {
    __syncthreads();
#pragma unroll
    for (int i = 0; i < 4; ++i) {
      const int c = i * 256 + tid;
      gll16(gA[i] + kt * 64, &sA[c * 8]);
      gll16(gB[i] + kt * 64, &sB[c * 8]);
    }
    __syncthreads();
#pragma unroll
    for (int ks = 0; ks < 2; ++ks) {
      bf16x8 a[4], bb[4];
#pragma unroll
      for (int mi = 0; mi < 4; ++mi) {
        const int row = wr + mi * 16 + (lane & 15);
        const int p = (ks * 4 + (lane >> 4) + row) & 7;
        a[mi] = *(const bf16x8*)&sA[row * 64 + p * 8];
      }
#pragma unroll
      for (int ni = 0; ni < 4; ++ni) {
        const int row = wc + ni * 16 + (lane & 15);
        const int p = (ks * 4 + (lane >> 4) + row) & 7;
        bb[ni] = *(const bf16x8*)&sB[row * 64 + p * 8];
      }
      __builtin_amdgcn_s_setprio(1);
#pragma unroll
      for (int mi = 0; mi < 4; ++mi)
#pragma unroll
        for (int ni = 0; ni < 4; ++ni)
          acc[mi][ni] = __builtin_amdgcn_mfma_f32_16x16x32_bf16(a[mi], bb[ni], acc[mi][ni], 0, 0, 0);
      __builtin_amdgcn_s_setprio(0);
    }
  }

#pragma unroll
  for (int mi = 0; mi < 4; ++mi) {
    const int r0 = wr + mi * 16 + ((lane >> 4) * 4);
#pragma unroll
    for (int ni = 0; ni < 4; ++ni) {
      const int col = nbase + wc + ni * 16 + (lane & 15);
#pragma unroll
      for (int j = 0; j < 4; ++j) {
        const int sid = sTok[r0 + j];
        __hip_bfloat16 hv = __float2bfloat16(acc[mi][ni][j]);
        slot[(size_t)sid * D_MODEL + col] = *(const ushort_t*)&hv;
      }
    }
  }
}

// ---------------- combine: out[t] = slot[2t] + slot[2t+1] ----------------
__global__ void __launch_bounds__(256) combine_kernel(
    const ushort_t* __restrict__ slot, float* __restrict__ out) {
  const int i = blockIdx.x * 256 + threadIdx.x;   // over T*D/8
  const int t = i >> 7;
  const int c = (i & 127) << 3;
  const size_t b0 = ((size_t)(t << 1)) * D_MODEL + c;
  const ushort8 a = *(const ushort8*)&slot[b0];
  const ushort8 b = *(const ushort8*)&slot[b0 + D_MODEL];
  float4 o0, o1;
  o0.x = bf2f(a[0]) + bf2f(b[0]); o0.y = bf2f(a[1]) + bf2f(b[1]);
  o0.z = bf2f(a[2]) + bf2f(b[2]); o0.w = bf2f(a[3]) + bf2f(b[3]);
  o1.x = bf2f(a[4]) + bf2f(b[4]); o1.y = bf2f(a[5]) + bf2f(b[5]);
  o1.z = bf2f(a[6]) + bf2f(b[6]); o1.w = bf2f(a[7]) + bf2f(b[7]);
  ((float4*)out)[i * 2] = o0;
  ((float4*)out)[i * 2 + 1] = o1;
}

// ---------------- launch ----------------
extern "C" void kernel_launch(void* const* d_in, const int* in_sizes, int n_in,
                              void* d_out, int out_size, void* d_ws, size_t ws_size,
                              hipStream_t stream) {
  (void)in_sizes; (void)n_in; (void)ws_size; (void)out_size;
  const float* x  = (const float*)d_in[0];
  const float* rw = (const float*)d_in[1];
  const float* wg = (const float*)d_in[2];
  const float* wu = (const float*)d_in[3];
  const float* wd = (const float*)d_in[4];
  float* out = (float*)d_out;

  char* ws = (char*)d_ws;
  size_t off = 0;
  auto alloc = [&](size_t bytes) -> char* {
    char* p = ws + off;
    off += (bytes + 255) & ~(size_t)255;
    return p;
  };

  int*   ctrl   = (int*)alloc(512);
  int*   topidx = (int*)alloc((size_t)T_TOKENS * 2 * 4);
  float* topw   = (float*)alloc((size_t)T_TOKENS * 2 * 4);
  int*   rowmap = (int*)alloc((size_t)MAXROWS * 4);
  float* roww   = (float*)alloc((size_t)MAXROWS * 4);
  __hip_bfloat16* xb   = (__hip_bfloat16*)alloc((size_t)T_TOKENS * D_MODEL * 2);
  __hip_bfloat16* wcat = (__hip_bfloat16*)alloc((size_t)N_EXP * N_CAT * D_MODEL * 2);
  __hip_bfloat16* Hbuf = (__hip_bfloat16*)alloc((size_t)MAXROWS * I_PAD * 2);
  ushort_t* slotout = (ushort_t*)alloc((size_t)(2 * T_TOKENS + 1) * D_MODEL * 2);
  // wdt aliases wcat (wcat dead after gemm1; wdt transpose runs after gemm1)
  __hip_bfloat16* wdt = wcat;

  hipMemsetAsync(ctrl, 0, 256, stream);

  cvt_x_kernel<<<(T_TOKENS * D_MODEL / 4 + 255) / 256, 256, 0, stream>>>(
      x, xb, T_TOKENS * D_MODEL / 4);

  // wg [E][1024][2752] -> wcat gate rows; wu -> wcat up rows
  transpose_cvt_kernel<<<dim3(D_MODEL / 64, I_PAD / 64, N_EXP), 256, 0, stream>>>(
      wg, wcat, D_MODEL, I_RAW, D_MODEL, (long)D_MODEL * I_RAW, (long)N_CAT * D_MODEL, 1);
  transpose_cvt_kernel<<<dim3(D_MODEL / 64, I_PAD / 64, N_EXP), 256, 0, stream>>>(
      wu, wcat, D_MODEL, I_RAW, D_MODEL, (long)D_MODEL * I_RAW, (long)N_CAT * D_MODEL, 2);

  router_kernel<<<T_TOKENS, 64, 0, stream>>>(x, rw, topidx, topw);
  hist_kernel<<<(2 * T_TOKENS) / 512, 512, 0, stream>>>(topidx, ctrl);
  padfill_kernel<<<(MAXROWS + 255) / 256, 256, 0, stream>>>(rowmap, roww);
  scan_kernel<<<1, 64, 0, stream>>>(ctrl);
  scatter_kernel<<<(2 * T_TOKENS) / 512, 512, 0, stream>>>(topidx, topw, ctrl, rowmap, roww);

  gemm1_kernel<<<dim3(NYT * 22), 512, 0, stream>>>(
      xb, wcat, Hbuf, rowmap, roww, ctrl);

  // wd [E][2752][1024] -> wdt [E][1024][2816]  (into wcat's space, after gemm1)
  transpose_cvt_kernel<<<dim3(I_PAD / 64, D_MODEL / 64, N_EXP), 256, 0, stream>>>(
      wd, wdt, I_RAW, D_MODEL, I_PAD, (long)I_RAW * D_MODEL, (long)D_MODEL * I_PAD, 0);

  gemm2_kernel<<<dim3(NYT * 2 * 8), 256, 0, stream>>>(
      Hbuf, wdt, slotout, rowmap, ctrl);

  combine_kernel<<<(T_TOKENS * D_MODEL / 8) / 256, 256, 0, stream>>>(slotout, out);
}